// Round 12
// baseline (4521.143 us; speedup 1.0000x reference)
//
#include <hip/hip_runtime.h>
#include <hip/hip_fp16.h>
#include <math.h>

#define B_ 64
#define T_ 512

typedef _Float16 h2_t __attribute__((ext_vector_type(2)));

__device__ __forceinline__ float fdot2u(unsigned int a, unsigned int b, float c) {
#if __has_builtin(__builtin_amdgcn_fdot2)
    return __builtin_amdgcn_fdot2(__builtin_bit_cast(h2_t, a),
                                  __builtin_bit_cast(h2_t, b), c, false);
#else
    const __half2 ah = __builtin_bit_cast(__half2, a);
    const __half2 bh = __builtin_bit_cast(__half2, b);
    const float2 af = __half22float2(ah), bf = __half22float2(bh);
    return c + af.x * bf.x + af.y * bf.y;
#endif
}
__device__ __forceinline__ unsigned int pack_h2(float x, float y) {
    const __half2 h = __float22half2_rn(make_float2(x, y));
    return __builtin_bit_cast(unsigned int, h);
}
__device__ __forceinline__ float ubits(unsigned int a) { return __builtin_bit_cast(float, a); }
__device__ __forceinline__ unsigned short f2h_bits(float x) {
    return __builtin_bit_cast(unsigned short, (_Float16)x);
}
__device__ __forceinline__ float h2f_bits(unsigned int bits) {
    return (float)__builtin_bit_cast(_Float16, (unsigned short)(bits & 0xffffu));
}

__device__ __forceinline__ float fsig(float z) { return 1.f / (1.f + __expf(-z)); }
__device__ __forceinline__ float ftanh(float z) {
    const float e = __expf(2.f * z);
    return 1.f - 2.f / (e + 1.f);
}

// ---------------------------------------------------------------------------
// GEMM: C[M,N] = (A[M,K]*mask)@W[K,N] + bias, packed-fp16 dot2 (r10, verified)
// ---------------------------------------------------------------------------
__global__ __launch_bounds__(256) void gemm_mask_f16(
    const float* __restrict__ A, const float* __restrict__ W,
    const float* __restrict__ bias, const float* __restrict__ mask,
    float* __restrict__ C, int M, int N, int K)
{
    const int TM = 64, TN = 64, TK = 32, KP = 16;
    __shared__ __align__(16) unsigned int As2[KP][68];
    __shared__ __align__(16) unsigned int Bs2[KP][68];

    const int tid = threadIdx.x;
    const int bn = blockIdx.x;
    const int bm = blockIdx.y;
    const int row0 = bm * TM;
    const int b = row0 / T_;

    const int ty = tid >> 4;
    const int tx = tid & 15;
    const int m0 = ty * 4;
    const int n0 = tx * 4;

    float acc[4][4];
#pragma unroll
    for (int i = 0; i < 4; i++)
#pragma unroll
        for (int j = 0; j < 4; j++) acc[i][j] = 0.f;

    for (int kk = 0; kk < K; kk += TK) {
        {
            const int m = tid >> 2;
            const int kq = (tid & 3) * 8;
            const float4 mv0 = *(const float4*)(mask + (size_t)b * K + kk + kq);
            const float4 mv1 = *(const float4*)(mask + (size_t)b * K + kk + kq + 4);
            const float4 a0 = *(const float4*)(A + (size_t)(row0 + m) * K + kk + kq);
            const float4 a1 = *(const float4*)(A + (size_t)(row0 + m) * K + kk + kq + 4);
            As2[kq / 2 + 0][m] = pack_h2(a0.x * mv0.x, a0.y * mv0.y);
            As2[kq / 2 + 1][m] = pack_h2(a0.z * mv0.z, a0.w * mv0.w);
            As2[kq / 2 + 2][m] = pack_h2(a1.x * mv1.x, a1.y * mv1.y);
            As2[kq / 2 + 3][m] = pack_h2(a1.z * mv1.z, a1.w * mv1.w);
        }
        {
            const int kp = tid >> 4;
            const int nq = (tid & 15) * 4;
            const float4 w0 = *(const float4*)(W + (size_t)(kk + 2 * kp) * N + bn * TN + nq);
            const float4 w1 = *(const float4*)(W + (size_t)(kk + 2 * kp + 1) * N + bn * TN + nq);
            uint4 pv;
            pv.x = pack_h2(w0.x, w1.x);
            pv.y = pack_h2(w0.y, w1.y);
            pv.z = pack_h2(w0.z, w1.z);
            pv.w = pack_h2(w0.w, w1.w);
            *(uint4*)&Bs2[kp][nq] = pv;
        }
        __syncthreads();

#pragma unroll
        for (int kp = 0; kp < KP; kp++) {
            const uint4 a4 = *(const uint4*)&As2[kp][m0];
            const uint4 b4 = *(const uint4*)&Bs2[kp][n0];
            acc[0][0] = fdot2u(a4.x, b4.x, acc[0][0]); acc[0][1] = fdot2u(a4.x, b4.y, acc[0][1]);
            acc[0][2] = fdot2u(a4.x, b4.z, acc[0][2]); acc[0][3] = fdot2u(a4.x, b4.w, acc[0][3]);
            acc[1][0] = fdot2u(a4.y, b4.x, acc[1][0]); acc[1][1] = fdot2u(a4.y, b4.y, acc[1][1]);
            acc[1][2] = fdot2u(a4.y, b4.z, acc[1][2]); acc[1][3] = fdot2u(a4.y, b4.w, acc[1][3]);
            acc[2][0] = fdot2u(a4.z, b4.x, acc[2][0]); acc[2][1] = fdot2u(a4.z, b4.y, acc[2][1]);
            acc[2][2] = fdot2u(a4.z, b4.z, acc[2][2]); acc[2][3] = fdot2u(a4.z, b4.w, acc[2][3]);
            acc[3][0] = fdot2u(a4.w, b4.x, acc[3][0]); acc[3][1] = fdot2u(a4.w, b4.y, acc[3][1]);
            acc[3][2] = fdot2u(a4.w, b4.z, acc[3][2]); acc[3][3] = fdot2u(a4.w, b4.w, acc[3][3]);
        }
        __syncthreads();
    }

    const float4 bv = *(const float4*)(bias + bn * TN + n0);
#pragma unroll
    for (int i = 0; i < 4; i++) {
        float4 v;
        v.x = acc[i][0] + bv.x;
        v.y = acc[i][1] + bv.y;
        v.z = acc[i][2] + bv.z;
        v.w = acc[i][3] + bv.w;
        *(float4*)&C[(size_t)(row0 + m0 + i) * N + bn * TN + n0] = v;
    }
}

// ---------------------------------------------------------------------------
// LSTM recurrence v12 = v11 with the HN=128 deadlock fixed.
// r11 bug: pull_check guard was `else if (tid < 128)` off `if (tid < HB)`;
// for HN=128 (HB=32) threads 32..63 entered the pull role with lane = tid-64
// NEGATIVE -> OOB loads -> tags never matched -> layer-2 deadlock. Pull role
// is now explicitly wave1: `tid >= 64 && tid < 128`, both phases.
// Design (unchanged): block (q,p) serves batches bA=2p, bB=2p+1 with one
// shared U quarter in LDS. A-phase dot/red/cell/publish, B-phase same; each
// batch's pull is ISSUED right after its publish and CHECKED one full phase
// (~1800 cy > RT ~900 cy) later -> L3 round-trip hidden behind the other
// batch's dot. 4 cols/thread: all LDS reads b128 (lanes stride 16B, free).
// Tagged-word protocol (v10-verified): word={tag,fp16 h}; parity dbuf bounds
// skew to 1 step; overwrite is transitively gated on the slow block's read.
// ---------------------------------------------------------------------------
template <int HN, bool F16>
__global__ __launch_bounds__(1024) void lstm_rec_v12(
    const float* __restrict__ xz,       // [B, T, 4*HN]
    const float* __restrict__ U,        // [HN, 4*HN]
    float* __restrict__ hout,           // [B, T, HN] or nullptr
    float* __restrict__ out_last,       // [B, HN] or nullptr
    unsigned int* __restrict__ hbuf)    // [2][B_*HN] tagged words
{
    constexpr int GATES = 4 * HN;
    constexpr int COLS = HN;
    constexpr int CQ = COLS / 4;          // column-quads (64 or 32)
    constexpr int NKG = 1024 / CQ;        // k-groups (16 or 32)
    constexpr int HB = HN / 4;            // hidden units per block (64 or 32)
    constexpr int KWORDS = F16 ? HN / 2 : HN;
    constexpr int WPT = KWORDS / NKG;     // words per thread (8 or 4)

    __shared__ __align__(16) unsigned int UW2[KWORDS * COLS];  // [w][c]
    __shared__ __align__(16) unsigned int hWA[KWORDS];
    __shared__ __align__(16) unsigned int hWB[KWORDS];
    __shared__ __align__(16) float4 zpart[NKG * CQ];
    __shared__ __align__(16) float act_sh[COLS];

    const int tid = threadIdx.x;
    const int q = blockIdx.x >> 5;        // quarter 0..3
    const int p = blockIdx.x & 31;        // batch-pair
    const int bA = 2 * p, bB = 2 * p + 1;

    const int cq = tid % CQ;
    const int kq = tid / CQ;
    const int c0 = 4 * cq;
    const int group = c0 / HB;            // gate 0..3 (quad within one gate)
    const int gcol = group * HN + q * HB + (c0 % HB);
    const int wbase = kq * WPT;
    const bool red = (kq == NKG - 1);
    const bool tanh_gate = (group == 2);
    const bool puller = (tid >= 64 && tid < 128);   // wave1 = pull role
    const int lane = tid - 64;

    // ---- one-time: stage U quarter into LDS, layout [w][c] ----
    {
        constexpr int NP = 1024 / COLS;
        const int c = tid % COLS;
        const int part = tid / COLS;
        const int gg = c / HB;
        const int gc = gg * HN + q * HB + (c % HB);
        for (int w = part; w < KWORDS; w += NP) {
            unsigned int word;
            if constexpr (F16) {
                word = pack_h2(U[(size_t)(2 * w) * GATES + gc],
                               U[(size_t)(2 * w + 1) * GATES + gc]);
            } else {
                word = __builtin_bit_cast(unsigned int, U[(size_t)w * GATES + gc]);
            }
            UW2[w * COLS + c] = word;
        }
    }
    if (tid < KWORDS) { hWA[tid] = 0u; hWB[tid] = 0u; }

    const float* xzbA = xz + (size_t)bA * T_ * GATES + gcol;
    const float* xzbB = xz + (size_t)bB * T_ * GATES + gcol;

    float cstA = 0.f, cstB = 0.f;
    float4 z0A = make_float4(0, 0, 0, 0), z0B = make_float4(0, 0, 0, 0);
    if (red) { z0A = *(const float4*)xzbA; z0B = *(const float4*)xzbB; }
    unsigned long long pAv0 = 0, pAv1 = 0, pBv0 = 0, pBv1 = 0;
    __syncthreads();

    // --- helpers ---
    auto dot = [&](const unsigned int* __restrict__ hW) -> float4 {
        float4 acc = make_float4(0.f, 0.f, 0.f, 0.f);
#pragma unroll
        for (int j = 0; j < WPT; j += 4) {
            const int w = wbase + j;
            const uint4 h4 = *(const uint4*)&hW[w];
            const uint4 uA = *(const uint4*)&UW2[(w + 0) * COLS + c0];
            const uint4 uB = *(const uint4*)&UW2[(w + 1) * COLS + c0];
            const uint4 uC = *(const uint4*)&UW2[(w + 2) * COLS + c0];
            const uint4 uD = *(const uint4*)&UW2[(w + 3) * COLS + c0];
            if constexpr (F16) {
                acc.x = fdot2u(uA.x, h4.x, acc.x); acc.y = fdot2u(uA.y, h4.x, acc.y);
                acc.z = fdot2u(uA.z, h4.x, acc.z); acc.w = fdot2u(uA.w, h4.x, acc.w);
                acc.x = fdot2u(uB.x, h4.y, acc.x); acc.y = fdot2u(uB.y, h4.y, acc.y);
                acc.z = fdot2u(uB.z, h4.y, acc.z); acc.w = fdot2u(uB.w, h4.y, acc.w);
                acc.x = fdot2u(uC.x, h4.z, acc.x); acc.y = fdot2u(uC.y, h4.z, acc.y);
                acc.z = fdot2u(uC.z, h4.z, acc.z); acc.w = fdot2u(uC.w, h4.z, acc.w);
                acc.x = fdot2u(uD.x, h4.w, acc.x); acc.y = fdot2u(uD.y, h4.w, acc.y);
                acc.z = fdot2u(uD.z, h4.w, acc.z); acc.w = fdot2u(uD.w, h4.w, acc.w);
            } else {
                const float h0 = ubits(h4.x), h1 = ubits(h4.y);
                const float h2 = ubits(h4.z), h3 = ubits(h4.w);
                acc.x += ubits(uA.x) * h0; acc.y += ubits(uA.y) * h0;
                acc.z += ubits(uA.z) * h0; acc.w += ubits(uA.w) * h0;
                acc.x += ubits(uB.x) * h1; acc.y += ubits(uB.y) * h1;
                acc.z += ubits(uB.z) * h1; acc.w += ubits(uB.w) * h1;
                acc.x += ubits(uC.x) * h2; acc.y += ubits(uC.y) * h2;
                acc.z += ubits(uC.z) * h2; acc.w += ubits(uC.w) * h2;
                acc.x += ubits(uD.x) * h3; acc.y += ubits(uD.y) * h3;
                acc.z += ubits(uD.z) * h3; acc.w += ubits(uD.w) * h3;
            }
        }
        return acc;
    };
    auto redact = [&](const float4& z0v) {
        float4 z = z0v;
#pragma unroll
        for (int r = 0; r < NKG; ++r) {
            const float4 pp = zpart[r * CQ + cq];
            z.x += pp.x; z.y += pp.y; z.z += pp.z; z.w += pp.w;
        }
        float4 a;
        if (tanh_gate) { a.x = ftanh(z.x); a.y = ftanh(z.y); a.z = ftanh(z.z); a.w = ftanh(z.w); }
        else           { a.x = fsig(z.x);  a.y = fsig(z.y);  a.z = fsig(z.z);  a.w = fsig(z.w);  }
        *(float4*)&act_sh[c0] = a;
    };
    auto cell = [&](float& cst) -> float {
        const float ig = act_sh[tid];
        const float fg = act_sh[HB + tid];
        const float gg = act_sh[2 * HB + tid];
        const float og = act_sh[3 * HB + tid];
        cst = fg * cst + ig * gg;
        return og * ftanh(cst);
    };
    auto pub = [&](int s, int b, unsigned int tag, float hnew) {
        unsigned int* hslot = hbuf + (size_t)s * B_ * HN + (size_t)b * HN;
        const unsigned int word = (tag << 16) | (unsigned int)f2h_bits(hnew);
        __hip_atomic_store(&hslot[q * HB + tid], word,
                           __ATOMIC_RELAXED, __HIP_MEMORY_SCOPE_AGENT);
    };
    auto pull_issue = [&](int s, int b, unsigned long long& v0, unsigned long long& v1) {
        const unsigned long long* hq =
            (const unsigned long long*)(hbuf + (size_t)s * B_ * HN + (size_t)b * HN);
        if constexpr (HN == 256) {
            v0 = __hip_atomic_load(&hq[2 * lane], __ATOMIC_RELAXED, __HIP_MEMORY_SCOPE_AGENT);
            v1 = __hip_atomic_load(&hq[2 * lane + 1], __ATOMIC_RELAXED, __HIP_MEMORY_SCOPE_AGENT);
        } else {
            v0 = __hip_atomic_load(&hq[lane], __ATOMIC_RELAXED, __HIP_MEMORY_SCOPE_AGENT);
        }
    };
    auto pull_check = [&](int s, int b, unsigned int tag,
                          unsigned long long& v0, unsigned long long& v1,
                          unsigned int* __restrict__ hW) {
        const unsigned long long* hq =
            (const unsigned long long*)(hbuf + (size_t)s * B_ * HN + (size_t)b * HN);
        const unsigned long long t64 = tag;
        if constexpr (HN == 256) {
            while (((v0 >> 16) & 0xffffull) != t64 || (v0 >> 48) != t64)
                v0 = __hip_atomic_load(&hq[2 * lane], __ATOMIC_RELAXED, __HIP_MEMORY_SCOPE_AGENT);
            while (((v1 >> 16) & 0xffffull) != t64 || (v1 >> 48) != t64)
                v1 = __hip_atomic_load(&hq[2 * lane + 1], __ATOMIC_RELAXED, __HIP_MEMORY_SCOPE_AGENT);
            hW[2 * lane] = (unsigned int)(v0 & 0xffffu) |
                           ((unsigned int)((v0 >> 32) & 0xffffu) << 16);
            hW[2 * lane + 1] = (unsigned int)(v1 & 0xffffu) |
                               ((unsigned int)((v1 >> 32) & 0xffffu) << 16);
        } else {
            while (((v0 >> 16) & 0xffffull) != t64 || (v0 >> 48) != t64)
                v0 = __hip_atomic_load(&hq[lane], __ATOMIC_RELAXED, __HIP_MEMORY_SCOPE_AGENT);
            hW[2 * lane] = __builtin_bit_cast(unsigned int, h2f_bits((unsigned int)v0));
            hW[2 * lane + 1] = __builtin_bit_cast(unsigned int, h2f_bits((unsigned int)(v0 >> 32)));
        }
    };

#pragma unroll 1
    for (int t = 0; t < T_; ++t) {
        const int s = t & 1;
        const unsigned int tag = (unsigned int)(t + 1);

        // ===== A phase =====
        zpart[kq * CQ + cq] = dot(hWA);
        __syncthreads();                                    // bar1
        if (red) {
            redact(z0A);
            if (t + 1 < T_) z0A = *(const float4*)(xzbA + (size_t)(t + 1) * GATES);
        }
        __syncthreads();                                    // bar2
        if (tid < HB) {
            const float hnewA = cell(cstA);
            if (t < T_ - 1) pub(s, bA, tag, hnewA);
            if (hout) hout[((size_t)bA * T_ + t) * HN + q * HB + tid] = hnewA;
            if (out_last && t == T_ - 1) out_last[(size_t)bA * HN + q * HB + tid] = hnewA;
        } else if (puller && t > 0) {
            // hB(t-1) published with tag t into slot (t-1)&1; issued last iter
            pull_check((t - 1) & 1, bB, (unsigned int)t, pBv0, pBv1, hWB);
        }
        __syncthreads();                                    // bar3
        if (t < T_ - 1 && puller)
            pull_issue(s, bA, pAv0, pAv1);                  // RT covered by B dot
        asm volatile("" ::: "memory");

        // ===== B phase =====
        zpart[kq * CQ + cq] = dot(hWB);
        __syncthreads();                                    // bar4
        if (red) {
            redact(z0B);
            if (t + 1 < T_) z0B = *(const float4*)(xzbB + (size_t)(t + 1) * GATES);
        }
        __syncthreads();                                    // bar5
        if (tid < HB) {
            const float hnewB = cell(cstB);
            if (t < T_ - 1) pub(s, bB, tag, hnewB);
            if (hout) hout[((size_t)bB * T_ + t) * HN + q * HB + tid] = hnewB;
            if (out_last && t == T_ - 1) out_last[(size_t)bB * HN + q * HB + tid] = hnewB;
        } else if (puller && t < T_ - 1) {
            pull_check(s, bA, tag, pAv0, pAv1, hWA);
        }
        __syncthreads();                                    // bar6
        if (t < T_ - 1 && puller)
            pull_issue(s, bB, pBv0, pBv1);                  // RT covered by next A dot
        asm volatile("" ::: "memory");
    }
}

// ---------------------------------------------------------------------------
// Launch
// ---------------------------------------------------------------------------
extern "C" void kernel_launch(void* const* d_in, const int* in_sizes, int n_in,
                              void* d_out, int out_size, void* d_ws, size_t ws_size,
                              hipStream_t stream)
{
    const float* x  = (const float*)d_in[0];
    const float* W0 = (const float*)d_in[1];
    const float* U0 = (const float*)d_in[2];
    const float* b0 = (const float*)d_in[3];
    const float* W1 = (const float*)d_in[4];
    const float* U1 = (const float*)d_in[5];
    const float* b1 = (const float*)d_in[6];
    const float* W2 = (const float*)d_in[7];
    const float* U2 = (const float*)d_in[8];
    const float* b2 = (const float*)d_in[9];
    const float* m0 = (const float*)d_in[10];
    const float* m1 = (const float*)d_in[11];
    const float* m2 = (const float*)d_in[12];
    float* out = (float*)d_out;

    // workspace layout:
    //   xz    : 134217728 B
    //   h0    :  33554432 B
    //   h1    :  33554432 B
    //   hbuf  : 3 regions x 131072 B (2 x 64 x 256 tagged words per layer)
    char* ws = (char*)d_ws;
    float* xz = (float*)ws;
    float* h0 = (float*)(ws + 134217728);
    float* h1 = (float*)(ws + 134217728 + 33554432);
    unsigned int* hb0 = (unsigned int*)(ws + 134217728 + 2 * 33554432);
    unsigned int* hb1 = hb0 + 2 * B_ * 256;
    unsigned int* hb2 = hb1 + 2 * B_ * 256;

    const int M = B_ * T_;  // 32768

    // Layer 0
    gemm_mask_f16<<<dim3(1024 / 64, M / 64), 256, 0, stream>>>(x, W0, b0, m0, xz, M, 1024, 128);
    lstm_rec_v12<256, true><<<128, 1024, 0, stream>>>(xz, U0, h0, nullptr, hb0);

    // Layer 1
    gemm_mask_f16<<<dim3(1024 / 64, M / 64), 256, 0, stream>>>(h0, W1, b1, m1, xz, M, 1024, 256);
    lstm_rec_v12<256, true><<<128, 1024, 0, stream>>>(xz, U1, h1, nullptr, hb1);

    // Layer 2 (H=128, fp32 LDS compute, fp16 exchange), emit last h only
    gemm_mask_f16<<<dim3(512 / 64, M / 64), 256, 0, stream>>>(h1, W2, b2, m2, xz, M, 512, 256);
    lstm_rec_v12<128, false><<<128, 1024, 0, stream>>>(xz, U2, nullptr, out, hb2);
}